// Round 3
// baseline (293.480 us; speedup 1.0000x reference)
//
#include <hip/hip_runtime.h>

#define NN 50000
#define NE 800000
#define FIN 256
#define FH 64
#define FL 32

#define SCAN_B 256
#define NBLK ((NN + SCAN_B - 1) / SCAN_B)   // 196

// ---------------- small utility kernels ----------------
__global__ __launch_bounds__(256) void k_zero_int(int* __restrict__ p, int n) {
    int i = blockIdx.x * 256 + threadIdx.x;
    if (i < n) p[i] = 0;
}

// int histogram of dst (in-degree, no self-loop)
__global__ __launch_bounds__(256) void k_hist(const int* __restrict__ dst,
                                              int* __restrict__ ideg) {
    int e = blockIdx.x * 256 + threadIdx.x;
    if (e < NE) atomicAdd(&ideg[dst[e]], 1);
}

// dinv = rsqrt(ideg + 1)   (self-loop included in degree)
__global__ __launch_bounds__(256) void k_dinv(const int* __restrict__ ideg,
                                              float* __restrict__ dinv) {
    int i = blockIdx.x * 256 + threadIdx.x;
    if (i < NN) dinv[i] = rsqrtf((float)(ideg[i] + 1));
}

// ---------------- hierarchical exclusive scan over ideg ----------------
__global__ __launch_bounds__(SCAN_B) void k_scan1(const int* __restrict__ ideg,
                                                  int* __restrict__ row_start,
                                                  int* __restrict__ partials) {
    __shared__ int tmp[SCAN_B];
    int tid = threadIdx.x;
    int i = blockIdx.x * SCAN_B + tid;
    int v = (i < NN) ? ideg[i] : 0;
    tmp[tid] = v;
    __syncthreads();
    for (int off = 1; off < SCAN_B; off <<= 1) {
        int t = (tid >= off) ? tmp[tid - off] : 0;
        __syncthreads();
        tmp[tid] += t;
        __syncthreads();
    }
    if (i < NN) row_start[i] = tmp[tid] - v;          // exclusive
    if (tid == SCAN_B - 1) partials[blockIdx.x] = tmp[tid];
}

__global__ __launch_bounds__(SCAN_B) void k_scan2(int* __restrict__ partials) {
    __shared__ int tmp[SCAN_B];
    int tid = threadIdx.x;
    int v = (tid < NBLK) ? partials[tid] : 0;
    tmp[tid] = v;
    __syncthreads();
    for (int off = 1; off < SCAN_B; off <<= 1) {
        int t = (tid >= off) ? tmp[tid - off] : 0;
        __syncthreads();
        tmp[tid] += t;
        __syncthreads();
    }
    if (tid < NBLK) partials[tid] = tmp[tid] - v;     // exclusive
}

__global__ __launch_bounds__(SCAN_B) void k_scan3(int* __restrict__ row_start,
                                                  const int* __restrict__ partials,
                                                  int* __restrict__ cursor) {
    int i = blockIdx.x * SCAN_B + threadIdx.x;
    if (i < NN) {
        int r = row_start[i] + partials[blockIdx.x];
        row_start[i] = r;
        cursor[i] = r;
    }
}

// fill CSR: csr_src[pos] = src[e], bucketed by dst
__global__ __launch_bounds__(256) void k_fill(const int* __restrict__ src,
                                              const int* __restrict__ dst,
                                              int* __restrict__ cursor,
                                              int* __restrict__ csr_src) {
    int e = blockIdx.x * 256 + threadIdx.x;
    if (e < NE) {
        int pos = atomicAdd(&cursor[dst[e]], 1);
        csr_src[pos] = src[e];
    }
}

// ---------------- GEMM1: h1 = x @ W1  [NN,256]x[256,64] ----------------
// 16 nodes/block. Thread t: node nl=t>>4, features 4*(t&15)..4*(t&15)+3.
// Per 4-k chunk: 1 ds_read_b128 (x) + 4 dwordx4 (W1 row slices) + 16 FMA.
// LDS traffic /4 vs 1-feature/thread version (was LDS-pipe-bound at ~55us).
__global__ __launch_bounds__(256) void k_gemm1(const float* __restrict__ x,
                                               const float* __restrict__ W1,
                                               float* __restrict__ h1) {
    __shared__ float xs[16][FIN + 4];  // +4 pad: nl-groups land in distinct banks
    int nb = blockIdx.x * 16;
    for (int idx = threadIdx.x; idx < 16 * (FIN / 4); idx += 256) {
        int r = idx >> 6;   // FIN/4 = 64 float4 per row
        int c = idx & 63;
        *(float4*)&xs[r][c * 4] = *(const float4*)&x[(size_t)(nb + r) * FIN + c * 4];
    }
    __syncthreads();

    int f0 = threadIdx.x & 15;   // feature group: 4*f0 .. 4*f0+3
    int nl = threadIdx.x >> 4;   // 0..15
    const float* wp = W1 + f0 * 4;
    float4 acc = make_float4(0.f, 0.f, 0.f, 0.f);
    #pragma unroll 4
    for (int k = 0; k < FIN; k += 4) {
        float4 xv = *(const float4*)&xs[nl][k];
        float4 w0 = *(const float4*)&wp[(k + 0) * FH];
        float4 w1 = *(const float4*)&wp[(k + 1) * FH];
        float4 w2 = *(const float4*)&wp[(k + 2) * FH];
        float4 w3 = *(const float4*)&wp[(k + 3) * FH];
        acc.x += xv.x * w0.x + xv.y * w1.x + xv.z * w2.x + xv.w * w3.x;
        acc.y += xv.x * w0.y + xv.y * w1.y + xv.z * w2.y + xv.w * w3.y;
        acc.z += xv.x * w0.z + xv.y * w1.z + xv.z * w2.z + xv.w * w3.z;
        acc.w += xv.x * w0.w + xv.y * w1.w + xv.z * w2.w + xv.w * w3.w;
    }
    *(float4*)&h1[(size_t)(nb + nl) * FH + f0 * 4] = acc;
}

// ---------------- gather1: h2 = relu(dinv[d]*(Σ dinv[s] h1[s] + dinv[d] h1[d]) + b1) ----------------
// 4 nodes per 256-thread block; 64 lanes (features) per node.
__global__ __launch_bounds__(256) void k_gather1(const float* __restrict__ h1,
                                                 const float* __restrict__ dinv,
                                                 const int* __restrict__ row_start,
                                                 const int* __restrict__ ideg,
                                                 const int* __restrict__ csr_src,
                                                 const float* __restrict__ b1,
                                                 float* __restrict__ h2) {
    int d = blockIdx.x * 4 + (threadIdx.x >> 6);
    int f = threadIdx.x & 63;
    if (d >= NN) return;
    int row = row_start[d];
    int cnt = ideg[d];
    float dd = dinv[d];
    float acc = h1[(size_t)d * FH + f] * dd;   // self-loop term
    int j = 0;
    for (; j + 2 <= cnt; j += 2) {
        int s0 = csr_src[row + j];
        int s1 = csr_src[row + j + 1];
        float w0 = dinv[s0], w1 = dinv[s1];
        acc += h1[(size_t)s0 * FH + f] * w0;
        acc += h1[(size_t)s1 * FH + f] * w1;
    }
    if (j < cnt) {
        int s0 = csr_src[row + j];
        acc += h1[(size_t)s0 * FH + f] * dinv[s0];
    }
    h2[(size_t)d * FH + f] = fmaxf(acc * dd + b1[f], 0.f);
}

// ---------------- GEMM2: h3 = h2 @ W2  [NN,64]x[64,32]  (h2 already relu'd) ----------------
// 32 nodes/block. Thread t: node nl=t>>3, features 4*(t&7)..4*(t&7)+3.
__global__ __launch_bounds__(256) void k_gemm2(const float* __restrict__ h2,
                                               const float* __restrict__ W2,
                                               float* __restrict__ h3) {
    __shared__ float xs[32][FH + 4];
    int nb = blockIdx.x * 32;
    int nrows = min(32, NN - nb);
    for (int idx = threadIdx.x; idx < nrows * (FH / 4); idx += 256) {
        int r = idx >> 4;   // FH/4 = 16 float4 per row
        int c = idx & 15;
        *(float4*)&xs[r][c * 4] = *(const float4*)&h2[(size_t)(nb + r) * FH + c * 4];
    }
    __syncthreads();

    int f0 = threadIdx.x & 7;    // feature group: 4*f0 .. 4*f0+3
    int nl = threadIdx.x >> 3;   // 0..31
    if (nl >= nrows) return;
    const float* wp = W2 + f0 * 4;
    float4 acc = make_float4(0.f, 0.f, 0.f, 0.f);
    #pragma unroll 4
    for (int k = 0; k < FH; k += 4) {
        float4 xv = *(const float4*)&xs[nl][k];
        float4 w0 = *(const float4*)&wp[(k + 0) * FL];
        float4 w1 = *(const float4*)&wp[(k + 1) * FL];
        float4 w2 = *(const float4*)&wp[(k + 2) * FL];
        float4 w3 = *(const float4*)&wp[(k + 3) * FL];
        acc.x += xv.x * w0.x + xv.y * w1.x + xv.z * w2.x + xv.w * w3.x;
        acc.y += xv.x * w0.y + xv.y * w1.y + xv.z * w2.y + xv.w * w3.y;
        acc.z += xv.x * w0.z + xv.y * w1.z + xv.z * w2.z + xv.w * w3.z;
        acc.w += xv.x * w0.w + xv.y * w1.w + xv.z * w2.w + xv.w * w3.w;
    }
    *(float4*)&h3[(size_t)(nb + nl) * FL + f0 * 4] = acc;
}

// ---------------- gather2: out = dinv[d]*(Σ dinv[s] h3[s] + dinv[d] h3[d]) + b2 ----------------
// 8 nodes per 256-thread block; 32 lanes per node.
__global__ __launch_bounds__(256) void k_gather2(const float* __restrict__ h3,
                                                 const float* __restrict__ dinv,
                                                 const int* __restrict__ row_start,
                                                 const int* __restrict__ ideg,
                                                 const int* __restrict__ csr_src,
                                                 const float* __restrict__ b2,
                                                 float* __restrict__ out) {
    int d = blockIdx.x * 8 + (threadIdx.x >> 5);
    int f = threadIdx.x & 31;
    if (d >= NN) return;
    int row = row_start[d];
    int cnt = ideg[d];
    float dd = dinv[d];
    float acc = h3[(size_t)d * FL + f] * dd;
    int j = 0;
    for (; j + 2 <= cnt; j += 2) {
        int s0 = csr_src[row + j];
        int s1 = csr_src[row + j + 1];
        float w0 = dinv[s0], w1 = dinv[s1];
        acc += h3[(size_t)s0 * FL + f] * w0;
        acc += h3[(size_t)s1 * FL + f] * w1;
    }
    if (j < cnt) {
        int s0 = csr_src[row + j];
        acc += h3[(size_t)s0 * FL + f] * dinv[s0];
    }
    out[(size_t)d * FL + f] = acc * dd + b2[f];
}

extern "C" void kernel_launch(void* const* d_in, const int* in_sizes, int n_in,
                              void* d_out, int out_size, void* d_ws, size_t ws_size,
                              hipStream_t stream) {
    const float* x  = (const float*)d_in[0];
    const int*   ei = (const int*)d_in[1];   // [2, NE] int32
    const float* W1 = (const float*)d_in[2];
    const float* b1 = (const float*)d_in[3];
    const float* W2 = (const float*)d_in[4];
    const float* b2 = (const float*)d_in[5];
    float* out = (float*)d_out;

    const int* src = ei;
    const int* dst = ei + NE;

    char* ws = (char*)d_ws;
    float* dinv     = (float*)(ws);
    int*   ideg     = (int*)(ws + (size_t)(0.25 * (1 << 20)));
    int*   partials = (int*)(ws + (size_t)(0.50 * (1 << 20)));
    int*   row_start= (int*)(ws + (size_t)(0.75 * (1 << 20)));
    int*   cursor   = (int*)(ws + (size_t)(1.00 * (1 << 20)));
    int*   csr_src  = (int*)(ws + (size_t)(1.25 * (1 << 20)));
    float* h1       = (float*)(ws + (size_t)45 * (1u << 20) / 10);   // 4.5 MB
    float* h2       = (float*)(ws + (size_t)175 * (1u << 20) / 10);  // 17.5 MB
    float* h3       = h1;  // alias: h1 dead after gather1

    // --- CSR build ---
    hipLaunchKernelGGL(k_zero_int, dim3((NN + 255) / 256), dim3(256), 0, stream, ideg, NN);
    hipLaunchKernelGGL(k_hist, dim3((NE + 255) / 256), dim3(256), 0, stream, dst, ideg);
    hipLaunchKernelGGL(k_dinv, dim3((NN + 255) / 256), dim3(256), 0, stream, ideg, dinv);
    hipLaunchKernelGGL(k_scan1, dim3(NBLK), dim3(SCAN_B), 0, stream, ideg, row_start, partials);
    hipLaunchKernelGGL(k_scan2, dim3(1), dim3(SCAN_B), 0, stream, partials);
    hipLaunchKernelGGL(k_scan3, dim3(NBLK), dim3(SCAN_B), 0, stream, row_start, partials, cursor);
    hipLaunchKernelGGL(k_fill, dim3((NE + 255) / 256), dim3(256), 0, stream, src, dst, cursor, csr_src);

    // --- layer 1 ---
    hipLaunchKernelGGL(k_gemm1, dim3(NN / 16), dim3(256), 0, stream, x, W1, h1);
    hipLaunchKernelGGL(k_gather1, dim3((NN + 3) / 4), dim3(256), 0, stream,
                       h1, dinv, row_start, ideg, csr_src, b1, h2);

    // --- layer 2 ---
    hipLaunchKernelGGL(k_gemm2, dim3((NN + 31) / 32), dim3(256), 0, stream, h2, W2, h3);
    hipLaunchKernelGGL(k_gather2, dim3((NN + 7) / 8), dim3(256), 0, stream,
                       h3, dinv, row_start, ideg, csr_src, b2, out);
}

// Round 4
// 244.945 us; speedup vs baseline: 1.1981x; 1.1981x over previous
//
#include <hip/hip_runtime.h>

#define NN 50000
#define NE 800000
#define FIN 256
#define FH 64
#define FL 32

#define SCAN_B 256
#define NBLK ((NN + SCAN_B - 1) / SCAN_B)   // 196

// ---------------- small utility kernels ----------------
__global__ __launch_bounds__(256) void k_zero_int(int* __restrict__ p, int n) {
    int i = blockIdx.x * 256 + threadIdx.x;
    if (i < n) p[i] = 0;
}

__global__ __launch_bounds__(256) void k_hist(const int* __restrict__ dst,
                                              int* __restrict__ ideg) {
    int e = blockIdx.x * 256 + threadIdx.x;
    if (e < NE) atomicAdd(&ideg[dst[e]], 1);
}

__global__ __launch_bounds__(256) void k_dinv(const int* __restrict__ ideg,
                                              float* __restrict__ dinv) {
    int i = blockIdx.x * 256 + threadIdx.x;
    if (i < NN) dinv[i] = rsqrtf((float)(ideg[i] + 1));
}

// ---------------- hierarchical exclusive scan over ideg ----------------
__global__ __launch_bounds__(SCAN_B) void k_scan1(const int* __restrict__ ideg,
                                                  int* __restrict__ row_start,
                                                  int* __restrict__ partials) {
    __shared__ int tmp[SCAN_B];
    int tid = threadIdx.x;
    int i = blockIdx.x * SCAN_B + tid;
    int v = (i < NN) ? ideg[i] : 0;
    tmp[tid] = v;
    __syncthreads();
    for (int off = 1; off < SCAN_B; off <<= 1) {
        int t = (tid >= off) ? tmp[tid - off] : 0;
        __syncthreads();
        tmp[tid] += t;
        __syncthreads();
    }
    if (i < NN) row_start[i] = tmp[tid] - v;          // exclusive
    if (tid == SCAN_B - 1) partials[blockIdx.x] = tmp[tid];
}

__global__ __launch_bounds__(SCAN_B) void k_scan2(int* __restrict__ partials) {
    __shared__ int tmp[SCAN_B];
    int tid = threadIdx.x;
    int v = (tid < NBLK) ? partials[tid] : 0;
    tmp[tid] = v;
    __syncthreads();
    for (int off = 1; off < SCAN_B; off <<= 1) {
        int t = (tid >= off) ? tmp[tid - off] : 0;
        __syncthreads();
        tmp[tid] += t;
        __syncthreads();
    }
    if (tid < NBLK) partials[tid] = tmp[tid] - v;     // exclusive
}

__global__ __launch_bounds__(SCAN_B) void k_scan3(int* __restrict__ row_start,
                                                  const int* __restrict__ partials,
                                                  int* __restrict__ cursor) {
    int i = blockIdx.x * SCAN_B + threadIdx.x;
    if (i < NN) {
        int r = row_start[i] + partials[blockIdx.x];
        row_start[i] = r;
        cursor[i] = r;
    }
}

__global__ __launch_bounds__(256) void k_fill(const int* __restrict__ src,
                                              const int* __restrict__ dst,
                                              int* __restrict__ cursor,
                                              int* __restrict__ csr_src) {
    int e = blockIdx.x * 256 + threadIdx.x;
    if (e < NE) {
        int pos = atomicAdd(&cursor[dst[e]], 1);
        csr_src[pos] = src[e];
    }
}

// ---------------- GEMM1: h1 = x @ W1  [NN,256]x[256,64] ----------------
// 64 nodes/block, 64KB LDS tile. Thread t: nodes 4*(t>>4)..+3, feats 4*(t&15)..+3.
// Per 4-k chunk: 4 ds_read_b128 (x) + 4 global dwordx4 (W1) + 64 FMA.
// Row r rotated by 4r floats (mod 256) so distinct-row reads hit distinct banks.
__global__ __launch_bounds__(256) void k_gemm1(const float* __restrict__ x,
                                               const float* __restrict__ W1,
                                               float* __restrict__ h1) {
    __shared__ float xs[64 * FIN];  // exactly 64 KB
    int nb = blockIdx.x * 64;
    for (int idx = threadIdx.x; idx < 64 * (FIN / 4); idx += 256) {
        int r = idx >> 6;            // 0..63
        int c = (idx & 63) * 4;      // 0..252
        float4 v = make_float4(0.f, 0.f, 0.f, 0.f);
        if (nb + r < NN) v = *(const float4*)&x[(size_t)(nb + r) * FIN + c];
        *(float4*)&xs[r * FIN + ((c + 4 * r) & (FIN - 1))] = v;
    }
    __syncthreads();

    int f0 = (threadIdx.x & 15) * 4;   // features f0..f0+3
    int n0 = (threadIdx.x >> 4) * 4;   // local nodes n0..n0+3
    const float* wp = W1 + f0;
    float4 a0 = make_float4(0.f, 0.f, 0.f, 0.f);
    float4 a1 = a0, a2 = a0, a3 = a0;
    #pragma unroll 2
    for (int k = 0; k < FIN; k += 4) {
        float4 w0 = *(const float4*)&wp[(k + 0) * FH];
        float4 w1 = *(const float4*)&wp[(k + 1) * FH];
        float4 w2 = *(const float4*)&wp[(k + 2) * FH];
        float4 w3 = *(const float4*)&wp[(k + 3) * FH];
        float4 x0 = *(const float4*)&xs[(n0 + 0) * FIN + ((k + 4 * (n0 + 0)) & (FIN - 1))];
        float4 x1 = *(const float4*)&xs[(n0 + 1) * FIN + ((k + 4 * (n0 + 1)) & (FIN - 1))];
        float4 x2 = *(const float4*)&xs[(n0 + 2) * FIN + ((k + 4 * (n0 + 2)) & (FIN - 1))];
        float4 x3 = *(const float4*)&xs[(n0 + 3) * FIN + ((k + 4 * (n0 + 3)) & (FIN - 1))];
        a0.x += x0.x*w0.x + x0.y*w1.x + x0.z*w2.x + x0.w*w3.x;
        a0.y += x0.x*w0.y + x0.y*w1.y + x0.z*w2.y + x0.w*w3.y;
        a0.z += x0.x*w0.z + x0.y*w1.z + x0.z*w2.z + x0.w*w3.z;
        a0.w += x0.x*w0.w + x0.y*w1.w + x0.z*w2.w + x0.w*w3.w;
        a1.x += x1.x*w0.x + x1.y*w1.x + x1.z*w2.x + x1.w*w3.x;
        a1.y += x1.x*w0.y + x1.y*w1.y + x1.z*w2.y + x1.w*w3.y;
        a1.z += x1.x*w0.z + x1.y*w1.z + x1.z*w2.z + x1.w*w3.z;
        a1.w += x1.x*w0.w + x1.y*w1.w + x1.z*w2.w + x1.w*w3.w;
        a2.x += x2.x*w0.x + x2.y*w1.x + x2.z*w2.x + x2.w*w3.x;
        a2.y += x2.x*w0.y + x2.y*w1.y + x2.z*w2.y + x2.w*w3.y;
        a2.z += x2.x*w0.z + x2.y*w1.z + x2.z*w2.z + x2.w*w3.z;
        a2.w += x2.x*w0.w + x2.y*w1.w + x2.z*w2.w + x2.w*w3.w;
        a3.x += x3.x*w0.x + x3.y*w1.x + x3.z*w2.x + x3.w*w3.x;
        a3.y += x3.x*w0.y + x3.y*w1.y + x3.z*w2.y + x3.w*w3.y;
        a3.z += x3.x*w0.z + x3.y*w1.z + x3.z*w2.z + x3.w*w3.z;
        a3.w += x3.x*w0.w + x3.y*w1.w + x3.z*w2.w + x3.w*w3.w;
    }
    int g0 = nb + n0;
    if (g0 + 0 < NN) *(float4*)&h1[(size_t)(g0 + 0) * FH + f0] = a0;
    if (g0 + 1 < NN) *(float4*)&h1[(size_t)(g0 + 1) * FH + f0] = a1;
    if (g0 + 2 < NN) *(float4*)&h1[(size_t)(g0 + 2) * FH + f0] = a2;
    if (g0 + 3 < NN) *(float4*)&h1[(size_t)(g0 + 3) * FH + f0] = a3;
}

// ---------------- gather1: h2 = relu(dinv[d]*(Σ dinv[s] h1[s] + dinv[d] h1[d]) + b1) ----------------
__global__ __launch_bounds__(256) void k_gather1(const float* __restrict__ h1,
                                                 const float* __restrict__ dinv,
                                                 const int* __restrict__ row_start,
                                                 const int* __restrict__ ideg,
                                                 const int* __restrict__ csr_src,
                                                 const float* __restrict__ b1,
                                                 float* __restrict__ h2) {
    int d = blockIdx.x * 4 + (threadIdx.x >> 6);
    int f = threadIdx.x & 63;
    if (d >= NN) return;
    int row = row_start[d];
    int cnt = ideg[d];
    float dd = dinv[d];
    float acc = h1[(size_t)d * FH + f] * dd;   // self-loop term
    int j = 0;
    for (; j + 2 <= cnt; j += 2) {
        int s0 = csr_src[row + j];
        int s1 = csr_src[row + j + 1];
        float w0 = dinv[s0], w1 = dinv[s1];
        acc += h1[(size_t)s0 * FH + f] * w0;
        acc += h1[(size_t)s1 * FH + f] * w1;
    }
    if (j < cnt) {
        int s0 = csr_src[row + j];
        acc += h1[(size_t)s0 * FH + f] * dinv[s0];
    }
    h2[(size_t)d * FH + f] = fmaxf(acc * dd + b1[f], 0.f);
}

// ---------------- GEMM2: h3 = h2 @ W2  [NN,64]x[64,32] ----------------
// 64 nodes/block, 16KB LDS. Thread t: nodes 2*(t>>3)..+1, feats 4*(t&7)..+3.
__global__ __launch_bounds__(256) void k_gemm2(const float* __restrict__ h2,
                                               const float* __restrict__ W2,
                                               float* __restrict__ h3) {
    __shared__ float xs[64 * FH];  // 16 KB
    int nb = blockIdx.x * 64;
    for (int idx = threadIdx.x; idx < 64 * (FH / 4); idx += 256) {
        int r = idx >> 4;            // 0..63
        int c = (idx & 15) * 4;      // 0..60
        float4 v = make_float4(0.f, 0.f, 0.f, 0.f);
        if (nb + r < NN) v = *(const float4*)&h2[(size_t)(nb + r) * FH + c];
        *(float4*)&xs[r * FH + ((c + 4 * r) & (FH - 1))] = v;
    }
    __syncthreads();

    int f0 = (threadIdx.x & 7) * 4;    // features f0..f0+3
    int n0 = (threadIdx.x >> 3) * 2;   // local nodes n0..n0+1
    const float* wp = W2 + f0;
    float4 a0 = make_float4(0.f, 0.f, 0.f, 0.f);
    float4 a1 = a0;
    #pragma unroll 4
    for (int k = 0; k < FH; k += 4) {
        float4 w0 = *(const float4*)&wp[(k + 0) * FL];
        float4 w1 = *(const float4*)&wp[(k + 1) * FL];
        float4 w2 = *(const float4*)&wp[(k + 2) * FL];
        float4 w3 = *(const float4*)&wp[(k + 3) * FL];
        float4 x0 = *(const float4*)&xs[(n0 + 0) * FH + ((k + 4 * (n0 + 0)) & (FH - 1))];
        float4 x1 = *(const float4*)&xs[(n0 + 1) * FH + ((k + 4 * (n0 + 1)) & (FH - 1))];
        a0.x += x0.x*w0.x + x0.y*w1.x + x0.z*w2.x + x0.w*w3.x;
        a0.y += x0.x*w0.y + x0.y*w1.y + x0.z*w2.y + x0.w*w3.y;
        a0.z += x0.x*w0.z + x0.y*w1.z + x0.z*w2.z + x0.w*w3.z;
        a0.w += x0.x*w0.w + x0.y*w1.w + x0.z*w2.w + x0.w*w3.w;
        a1.x += x1.x*w0.x + x1.y*w1.x + x1.z*w2.x + x1.w*w3.x;
        a1.y += x1.x*w0.y + x1.y*w1.y + x1.z*w2.y + x1.w*w3.y;
        a1.z += x1.x*w0.z + x1.y*w1.z + x1.z*w2.z + x1.w*w3.z;
        a1.w += x1.x*w0.w + x1.y*w1.w + x1.z*w2.w + x1.w*w3.w;
    }
    int g0 = nb + n0;
    if (g0 + 0 < NN) *(float4*)&h3[(size_t)(g0 + 0) * FL + f0] = a0;
    if (g0 + 1 < NN) *(float4*)&h3[(size_t)(g0 + 1) * FL + f0] = a1;
}

// ---------------- gather2: out = dinv[d]*(Σ dinv[s] h3[s] + dinv[d] h3[d]) + b2 ----------------
__global__ __launch_bounds__(256) void k_gather2(const float* __restrict__ h3,
                                                 const float* __restrict__ dinv,
                                                 const int* __restrict__ row_start,
                                                 const int* __restrict__ ideg,
                                                 const int* __restrict__ csr_src,
                                                 const float* __restrict__ b2,
                                                 float* __restrict__ out) {
    int d = blockIdx.x * 8 + (threadIdx.x >> 5);
    int f = threadIdx.x & 31;
    if (d >= NN) return;
    int row = row_start[d];
    int cnt = ideg[d];
    float dd = dinv[d];
    float acc = h3[(size_t)d * FL + f] * dd;
    int j = 0;
    for (; j + 2 <= cnt; j += 2) {
        int s0 = csr_src[row + j];
        int s1 = csr_src[row + j + 1];
        float w0 = dinv[s0], w1 = dinv[s1];
        acc += h3[(size_t)s0 * FL + f] * w0;
        acc += h3[(size_t)s1 * FL + f] * w1;
    }
    if (j < cnt) {
        int s0 = csr_src[row + j];
        acc += h3[(size_t)s0 * FL + f] * dinv[s0];
    }
    out[(size_t)d * FL + f] = acc * dd + b2[f];
}

extern "C" void kernel_launch(void* const* d_in, const int* in_sizes, int n_in,
                              void* d_out, int out_size, void* d_ws, size_t ws_size,
                              hipStream_t stream) {
    const float* x  = (const float*)d_in[0];
    const int*   ei = (const int*)d_in[1];   // [2, NE] int32
    const float* W1 = (const float*)d_in[2];
    const float* b1 = (const float*)d_in[3];
    const float* W2 = (const float*)d_in[4];
    const float* b2 = (const float*)d_in[5];
    float* out = (float*)d_out;

    const int* src = ei;
    const int* dst = ei + NE;

    char* ws = (char*)d_ws;
    float* dinv     = (float*)(ws);
    int*   ideg     = (int*)(ws + (size_t)(0.25 * (1 << 20)));
    int*   partials = (int*)(ws + (size_t)(0.50 * (1 << 20)));
    int*   row_start= (int*)(ws + (size_t)(0.75 * (1 << 20)));
    int*   cursor   = (int*)(ws + (size_t)(1.00 * (1 << 20)));
    int*   csr_src  = (int*)(ws + (size_t)(1.25 * (1 << 20)));
    float* h1       = (float*)(ws + (size_t)45 * (1u << 20) / 10);   // 4.5 MB
    float* h2       = (float*)(ws + (size_t)175 * (1u << 20) / 10);  // 17.5 MB
    float* h3       = h1;  // alias: h1 dead after gather1

    // --- CSR build ---
    hipLaunchKernelGGL(k_zero_int, dim3((NN + 255) / 256), dim3(256), 0, stream, ideg, NN);
    hipLaunchKernelGGL(k_hist, dim3((NE + 255) / 256), dim3(256), 0, stream, dst, ideg);
    hipLaunchKernelGGL(k_dinv, dim3((NN + 255) / 256), dim3(256), 0, stream, ideg, dinv);
    hipLaunchKernelGGL(k_scan1, dim3(NBLK), dim3(SCAN_B), 0, stream, ideg, row_start, partials);
    hipLaunchKernelGGL(k_scan2, dim3(1), dim3(SCAN_B), 0, stream, partials);
    hipLaunchKernelGGL(k_scan3, dim3(NBLK), dim3(SCAN_B), 0, stream, row_start, partials, cursor);
    hipLaunchKernelGGL(k_fill, dim3((NE + 255) / 256), dim3(256), 0, stream, src, dst, cursor, csr_src);

    // --- layer 1 ---
    hipLaunchKernelGGL(k_gemm1, dim3((NN + 63) / 64), dim3(256), 0, stream, x, W1, h1);
    hipLaunchKernelGGL(k_gather1, dim3((NN + 3) / 4), dim3(256), 0, stream,
                       h1, dinv, row_start, ideg, csr_src, b1, h2);

    // --- layer 2 ---
    hipLaunchKernelGGL(k_gemm2, dim3((NN + 63) / 64), dim3(256), 0, stream, h2, W2, h3);
    hipLaunchKernelGGL(k_gather2, dim3((NN + 7) / 8), dim3(256), 0, stream,
                       h3, dinv, row_start, ideg, csr_src, b2, out);
}

// Round 5
// 204.776 us; speedup vs baseline: 1.4332x; 1.1962x over previous
//
#include <hip/hip_runtime.h>

#define NN 50000
#define NE 800000
#define FIN 256
#define FH 64
#define FL 32

#define SCAN_B 256
#define NBLK ((NN + SCAN_B - 1) / SCAN_B)   // 196

typedef _Float16 half8 __attribute__((ext_vector_type(8)));
typedef _Float16 half4 __attribute__((ext_vector_type(4)));
typedef float f32x4 __attribute__((ext_vector_type(4)));

// ---------------- CSR build ----------------
__global__ __launch_bounds__(256) void k_hist(const int* __restrict__ dst,
                                              int* __restrict__ ideg) {
    int e = blockIdx.x * 256 + threadIdx.x;
    if (e < NE) atomicAdd(&ideg[dst[e]], 1);
}

__global__ __launch_bounds__(SCAN_B) void k_scan1(const int* __restrict__ ideg,
                                                  int* __restrict__ row_start,
                                                  int* __restrict__ partials) {
    __shared__ int tmp[SCAN_B];
    int tid = threadIdx.x;
    int i = blockIdx.x * SCAN_B + tid;
    int v = (i < NN) ? ideg[i] : 0;
    tmp[tid] = v;
    __syncthreads();
    for (int off = 1; off < SCAN_B; off <<= 1) {
        int t = (tid >= off) ? tmp[tid - off] : 0;
        __syncthreads();
        tmp[tid] += t;
        __syncthreads();
    }
    if (i < NN) row_start[i] = tmp[tid] - v;          // exclusive
    if (tid == SCAN_B - 1) partials[blockIdx.x] = tmp[tid];
}

__global__ __launch_bounds__(SCAN_B) void k_scan2(int* __restrict__ partials) {
    __shared__ int tmp[SCAN_B];
    int tid = threadIdx.x;
    int v = (tid < NBLK) ? partials[tid] : 0;
    tmp[tid] = v;
    __syncthreads();
    for (int off = 1; off < SCAN_B; off <<= 1) {
        int t = (tid >= off) ? tmp[tid - off] : 0;
        __syncthreads();
        tmp[tid] += t;
        __syncthreads();
    }
    if (tid < NBLK) partials[tid] = tmp[tid] - v;     // exclusive
}

// scan finalize + dinv (fused)
__global__ __launch_bounds__(SCAN_B) void k_scan3(int* __restrict__ row_start,
                                                  const int* __restrict__ partials,
                                                  int* __restrict__ cursor,
                                                  const int* __restrict__ ideg,
                                                  float* __restrict__ dinv) {
    int i = blockIdx.x * SCAN_B + threadIdx.x;
    if (i < NN) {
        int r = row_start[i] + partials[blockIdx.x];
        row_start[i] = r;
        cursor[i] = r;
        dinv[i] = rsqrtf((float)(ideg[i] + 1));
    }
}

__global__ __launch_bounds__(256) void k_fill(const int* __restrict__ src,
                                              const int* __restrict__ dst,
                                              int* __restrict__ cursor,
                                              int* __restrict__ csr_src) {
    int e = blockIdx.x * 256 + threadIdx.x;
    if (e < NE) {
        int pos = atomicAdd(&cursor[dst[e]], 1);
        csr_src[pos] = src[e];
    }
}

// ---------------- prep: wt_g = f16(W1^T)  [64][256] ----------------
__global__ __launch_bounds__(256) void k_prepW(const float* __restrict__ W1,
                                               _Float16* __restrict__ wt_g) {
    int i = blockIdx.x * 256 + threadIdx.x;   // coalesced read of W1[k][f]
    if (i < FIN * FH) {
        int k = i >> 6, f = i & 63;
        wt_g[f * FIN + k] = (_Float16)W1[i];
    }
}

// ---------------- GEMM1 via f16 MFMA: h1 = x @ W1  [NN,256]x[256,64] ----------------
// 64 nodes/block, 256 thr = 4 waves. Wave w: nodes 16w..16w+15, 4 C-tiles (f 0..63).
// K processed in two 128-panels staged in LDS as f16 (xs) + f16 W1^T (wt).
// A/B frags: lane l -> row/col = l&15, 8 consecutive k at (l>>4)*8 (consistent-k
// loading: correct for any shared bijective k-map). C/D: col=l&15, row=(l>>4)*4+reg.
#define KP 128
#define XS_LD 136   // 128 + 8 f16 pad: 272B row stride (16B aligned, spread banks)

__global__ __launch_bounds__(256) void k_gemm1(const float* __restrict__ x,
                                               const _Float16* __restrict__ wt_g,
                                               float* __restrict__ h1) {
    __shared__ _Float16 xs[64 * XS_LD];   // 17408 B
    __shared__ _Float16 wt[64 * XS_LD];   // 17408 B
    int nb = blockIdx.x * 64;
    int tid = threadIdx.x;
    int w = tid >> 6, l = tid & 63;
    int r16 = l & 15, g = l >> 4;

    f32x4 acc[4] = {{0.f,0.f,0.f,0.f},{0.f,0.f,0.f,0.f},{0.f,0.f,0.f,0.f},{0.f,0.f,0.f,0.f}};

    #pragma unroll
    for (int p = 0; p < 2; ++p) {
        int k0 = p * KP;
        __syncthreads();   // protect LDS from previous panel's readers
        // stage x panel: 64 rows x 128 k, f32 -> f16
        for (int i = tid; i < 64 * 32; i += 256) {
            int r = i >> 5, c = (i & 31) * 4;
            float4 v = make_float4(0.f, 0.f, 0.f, 0.f);
            if (nb + r < NN) v = *(const float4*)&x[(size_t)(nb + r) * FIN + k0 + c];
            half4 h; h[0] = (_Float16)v.x; h[1] = (_Float16)v.y;
                     h[2] = (_Float16)v.z; h[3] = (_Float16)v.w;
            *(half4*)&xs[r * XS_LD + c] = h;
        }
        // stage W1^T panel: 64 f-rows x 128 k (already f16 in global)
        for (int i = tid; i < 64 * 16; i += 256) {
            int r = i >> 4, c = (i & 15) * 8;
            *(half8*)&wt[r * XS_LD + c] = *(const half8*)&wt_g[r * FIN + k0 + c];
        }
        __syncthreads();
        // 4 MFMA k-steps of 32
        #pragma unroll
        for (int ks = 0; ks < 4; ++ks) {
            int kk = ks * 32 + g * 8;
            half8 a = *(const half8*)&xs[(w * 16 + r16) * XS_LD + kk];
            #pragma unroll
            for (int fb = 0; fb < 4; ++fb) {
                half8 b = *(const half8*)&wt[(fb * 16 + r16) * XS_LD + kk];
                acc[fb] = __builtin_amdgcn_mfma_f32_16x16x32_f16(a, b, acc[fb], 0, 0, 0);
            }
        }
    }
    // C write: node = nb + 16w + (l>>4)*4 + reg, feat = fb*16 + (l&15)
    int nodeb = nb + w * 16 + g * 4;
    #pragma unroll
    for (int fb = 0; fb < 4; ++fb) {
        #pragma unroll
        for (int r = 0; r < 4; ++r) {
            int node = nodeb + r;
            if (node < NN) h1[(size_t)node * FH + fb * 16 + r16] = acc[fb][r];
        }
    }
}

// ---------------- gather1: h2 = relu(dinv[d]*(Σ dinv[s] h1[s] + dinv[d] h1[d]) + b1) ----------------
__global__ __launch_bounds__(256) void k_gather1(const float* __restrict__ h1,
                                                 const float* __restrict__ dinv,
                                                 const int* __restrict__ row_start,
                                                 const int* __restrict__ ideg,
                                                 const int* __restrict__ csr_src,
                                                 const float* __restrict__ b1,
                                                 float* __restrict__ h2) {
    int d = blockIdx.x * 4 + (threadIdx.x >> 6);
    int f = threadIdx.x & 63;
    if (d >= NN) return;
    int row = row_start[d];
    int cnt = ideg[d];
    float dd = dinv[d];
    float acc = h1[(size_t)d * FH + f] * dd;   // self-loop term
    int j = 0;
    for (; j + 2 <= cnt; j += 2) {
        int s0 = csr_src[row + j];
        int s1 = csr_src[row + j + 1];
        float w0 = dinv[s0], w1 = dinv[s1];
        acc += h1[(size_t)s0 * FH + f] * w0;
        acc += h1[(size_t)s1 * FH + f] * w1;
    }
    if (j < cnt) {
        int s0 = csr_src[row + j];
        acc += h1[(size_t)s0 * FH + f] * dinv[s0];
    }
    h2[(size_t)d * FH + f] = fmaxf(acc * dd + b1[f], 0.f);
}

// ---------------- GEMM2: h3 = h2 @ W2  [NN,64]x[64,32]  (W2 = 8KB, L1-resident) ----------------
__global__ __launch_bounds__(256) void k_gemm2(const float* __restrict__ h2,
                                               const float* __restrict__ W2,
                                               float* __restrict__ h3) {
    __shared__ float xs[64 * FH];  // 16 KB
    int nb = blockIdx.x * 64;
    for (int idx = threadIdx.x; idx < 64 * (FH / 4); idx += 256) {
        int r = idx >> 4;
        int c = (idx & 15) * 4;
        float4 v = make_float4(0.f, 0.f, 0.f, 0.f);
        if (nb + r < NN) v = *(const float4*)&h2[(size_t)(nb + r) * FH + c];
        *(float4*)&xs[r * FH + ((c + 4 * r) & (FH - 1))] = v;
    }
    __syncthreads();

    int f0 = (threadIdx.x & 7) * 4;
    int n0 = (threadIdx.x >> 3) * 2;
    const float* wp = W2 + f0;
    float4 a0 = make_float4(0.f, 0.f, 0.f, 0.f);
    float4 a1 = a0;
    #pragma unroll 4
    for (int k = 0; k < FH; k += 4) {
        float4 w0 = *(const float4*)&wp[(k + 0) * FL];
        float4 w1 = *(const float4*)&wp[(k + 1) * FL];
        float4 w2 = *(const float4*)&wp[(k + 2) * FL];
        float4 w3 = *(const float4*)&wp[(k + 3) * FL];
        float4 x0 = *(const float4*)&xs[(n0 + 0) * FH + ((k + 4 * (n0 + 0)) & (FH - 1))];
        float4 x1 = *(const float4*)&xs[(n0 + 1) * FH + ((k + 4 * (n0 + 1)) & (FH - 1))];
        a0.x += x0.x*w0.x + x0.y*w1.x + x0.z*w2.x + x0.w*w3.x;
        a0.y += x0.x*w0.y + x0.y*w1.y + x0.z*w2.y + x0.w*w3.y;
        a0.z += x0.x*w0.z + x0.y*w1.z + x0.z*w2.z + x0.w*w3.z;
        a0.w += x0.x*w0.w + x0.y*w1.w + x0.z*w2.w + x0.w*w3.w;
        a1.x += x1.x*w0.x + x1.y*w1.x + x1.z*w2.x + x1.w*w3.x;
        a1.y += x1.x*w0.y + x1.y*w1.y + x1.z*w2.y + x1.w*w3.y;
        a1.z += x1.x*w0.z + x1.y*w1.z + x1.z*w2.z + x1.w*w3.z;
        a1.w += x1.x*w0.w + x1.y*w1.w + x1.z*w2.w + x1.w*w3.w;
    }
    int g0 = nb + n0;
    if (g0 + 0 < NN) *(float4*)&h3[(size_t)(g0 + 0) * FL + f0] = a0;
    if (g0 + 1 < NN) *(float4*)&h3[(size_t)(g0 + 1) * FL + f0] = a1;
}

// ---------------- gather2: out = dinv[d]*(Σ dinv[s] h3[s] + dinv[d] h3[d]) + b2 ----------------
__global__ __launch_bounds__(256) void k_gather2(const float* __restrict__ h3,
                                                 const float* __restrict__ dinv,
                                                 const int* __restrict__ row_start,
                                                 const int* __restrict__ ideg,
                                                 const int* __restrict__ csr_src,
                                                 const float* __restrict__ b2,
                                                 float* __restrict__ out) {
    int d = blockIdx.x * 8 + (threadIdx.x >> 5);
    int f = threadIdx.x & 31;
    if (d >= NN) return;
    int row = row_start[d];
    int cnt = ideg[d];
    float dd = dinv[d];
    float acc = h3[(size_t)d * FL + f] * dd;
    int j = 0;
    for (; j + 2 <= cnt; j += 2) {
        int s0 = csr_src[row + j];
        int s1 = csr_src[row + j + 1];
        float w0 = dinv[s0], w1 = dinv[s1];
        acc += h3[(size_t)s0 * FL + f] * w0;
        acc += h3[(size_t)s1 * FL + f] * w1;
    }
    if (j < cnt) {
        int s0 = csr_src[row + j];
        acc += h3[(size_t)s0 * FL + f] * dinv[s0];
    }
    out[(size_t)d * FL + f] = acc * dd + b2[f];
}

extern "C" void kernel_launch(void* const* d_in, const int* in_sizes, int n_in,
                              void* d_out, int out_size, void* d_ws, size_t ws_size,
                              hipStream_t stream) {
    const float* x  = (const float*)d_in[0];
    const int*   ei = (const int*)d_in[1];   // [2, NE] int32
    const float* W1 = (const float*)d_in[2];
    const float* b1 = (const float*)d_in[3];
    const float* W2 = (const float*)d_in[4];
    const float* b2 = (const float*)d_in[5];
    float* out = (float*)d_out;

    const int* src = ei;
    const int* dst = ei + NE;

    char* ws = (char*)d_ws;
    float*     dinv     = (float*)(ws);                                  // 200 KB
    int*       ideg     = (int*)(ws + (size_t)(0.25 * (1 << 20)));       // 200 KB
    int*       partials = (int*)(ws + (size_t)(0.50 * (1 << 20)));       // 1 KB
    _Float16*  wt_g     = (_Float16*)(ws + (size_t)(0.55 * (1 << 20)));  // 32 KB
    int*       row_start= (int*)(ws + (size_t)(0.75 * (1 << 20)));       // 200 KB
    int*       cursor   = (int*)(ws + (size_t)(1.00 * (1 << 20)));       // 200 KB
    int*       csr_src  = (int*)(ws + (size_t)(1.25 * (1 << 20)));       // 3.2 MB
    float*     h1       = (float*)(ws + (size_t)45 * (1u << 20) / 10);   // 12.8 MB @4.5MB
    float*     h2       = (float*)(ws + (size_t)175 * (1u << 20) / 10);  // 12.8 MB @17.5MB
    float*     h3       = h1;  // alias: h1 dead after gather1

    // --- CSR build + dinv ---
    hipMemsetAsync(ideg, 0, NN * sizeof(int), stream);
    hipLaunchKernelGGL(k_hist, dim3((NE + 255) / 256), dim3(256), 0, stream, dst, ideg);
    hipLaunchKernelGGL(k_scan1, dim3(NBLK), dim3(SCAN_B), 0, stream, ideg, row_start, partials);
    hipLaunchKernelGGL(k_scan2, dim3(1), dim3(SCAN_B), 0, stream, partials);
    hipLaunchKernelGGL(k_scan3, dim3(NBLK), dim3(SCAN_B), 0, stream, row_start, partials, cursor, ideg, dinv);
    hipLaunchKernelGGL(k_fill, dim3((NE + 255) / 256), dim3(256), 0, stream, src, dst, cursor, csr_src);

    // --- layer 1 ---
    hipLaunchKernelGGL(k_prepW, dim3((FIN * FH + 255) / 256), dim3(256), 0, stream, W1, wt_g);
    hipLaunchKernelGGL(k_gemm1, dim3((NN + 63) / 64), dim3(256), 0, stream, x, wt_g, h1);
    hipLaunchKernelGGL(k_gather1, dim3((NN + 3) / 4), dim3(256), 0, stream,
                       h1, dinv, row_start, ideg, csr_src, b1, h2);

    // --- layer 2 ---
    hipLaunchKernelGGL(k_gemm2, dim3((NN + 63) / 64), dim3(256), 0, stream, h2, W2, h3);
    hipLaunchKernelGGL(k_gather2, dim3((NN + 7) / 8), dim3(256), 0, stream,
                       h3, dinv, row_start, ideg, csr_src, b2, out);
}

// Round 6
// 188.046 us; speedup vs baseline: 1.5607x; 1.0890x over previous
//
#include <hip/hip_runtime.h>

#define NN 50000
#define NE 800000
#define FIN 256
#define FH 64
#define FL 32

#define SCAN_B 256
#define NBLK ((NN + SCAN_B - 1) / SCAN_B)   // 196

typedef _Float16 half8 __attribute__((ext_vector_type(8)));
typedef _Float16 half4 __attribute__((ext_vector_type(4)));
typedef float f32x4 __attribute__((ext_vector_type(4)));

// ---------------- CSR build ----------------
__global__ __launch_bounds__(256) void k_hist(const int* __restrict__ dst,
                                              int* __restrict__ ideg) {
    int e = blockIdx.x * 256 + threadIdx.x;
    if (e < NE) atomicAdd(&ideg[dst[e]], 1);
}

__global__ __launch_bounds__(SCAN_B) void k_scan1(const int* __restrict__ ideg,
                                                  int* __restrict__ row_start,
                                                  int* __restrict__ partials) {
    __shared__ int tmp[SCAN_B];
    int tid = threadIdx.x;
    int i = blockIdx.x * SCAN_B + tid;
    int v = (i < NN) ? ideg[i] : 0;
    tmp[tid] = v;
    __syncthreads();
    for (int off = 1; off < SCAN_B; off <<= 1) {
        int t = (tid >= off) ? tmp[tid - off] : 0;
        __syncthreads();
        tmp[tid] += t;
        __syncthreads();
    }
    if (i < NN) row_start[i] = tmp[tid] - v;          // exclusive
    if (tid == SCAN_B - 1) partials[blockIdx.x] = tmp[tid];
}

__global__ __launch_bounds__(SCAN_B) void k_scan2(int* __restrict__ partials) {
    __shared__ int tmp[SCAN_B];
    int tid = threadIdx.x;
    int v = (tid < NBLK) ? partials[tid] : 0;
    tmp[tid] = v;
    __syncthreads();
    for (int off = 1; off < SCAN_B; off <<= 1) {
        int t = (tid >= off) ? tmp[tid - off] : 0;
        __syncthreads();
        tmp[tid] += t;
        __syncthreads();
    }
    if (tid < NBLK) partials[tid] = tmp[tid] - v;     // exclusive
}

// scan finalize + dinv (fused)
__global__ __launch_bounds__(SCAN_B) void k_scan3(int* __restrict__ row_start,
                                                  const int* __restrict__ partials,
                                                  const int* __restrict__ ideg,
                                                  float* __restrict__ dinv) {
    int i = blockIdx.x * SCAN_B + threadIdx.x;
    if (i < NN) {
        row_start[i] = row_start[i] + partials[blockIdx.x];
        dinv[i] = rsqrtf((float)(ideg[i] + 1));
    }
}

// linked-list build: head[dst] -> chain of edges; nxt2[e] = {next_edge, src[e]}
// The 6.4MB nxt2 write is coalesced (e-indexed) -> no write amplification.
__global__ __launch_bounds__(256) void k_ll_build(const int* __restrict__ src,
                                                  const int* __restrict__ dst,
                                                  int* __restrict__ head,
                                                  int2* __restrict__ nxt2) {
    int e = blockIdx.x * 256 + threadIdx.x;
    if (e < NE) {
        int old = atomicExch(&head[dst[e]], e);
        nxt2[e] = make_int2(old, src[e]);
    }
}

// chain walk: one lane per dst, write csr_src[row_start[d]..] sequentially.
// Consecutive lanes own consecutive dst -> writes are block-local & dense.
__global__ __launch_bounds__(256) void k_walk(const int* __restrict__ head,
                                              const int2* __restrict__ nxt2,
                                              const int* __restrict__ row_start,
                                              int* __restrict__ csr_src) {
    int d = blockIdx.x * 256 + threadIdx.x;
    if (d < NN) {
        int cur = head[d];
        int pos = row_start[d];
        while (cur >= 0) {
            int2 v = nxt2[cur];
            csr_src[pos++] = v.y;
            cur = v.x;
        }
    }
}

// ---------------- prep: wt_g = f16(W1^T)  [64][256] ----------------
__global__ __launch_bounds__(256) void k_prepW(const float* __restrict__ W1,
                                               _Float16* __restrict__ wt_g) {
    int i = blockIdx.x * 256 + threadIdx.x;   // coalesced read of W1[k][f]
    if (i < FIN * FH) {
        int k = i >> 6, f = i & 63;
        wt_g[f * FIN + k] = (_Float16)W1[i];
    }
}

// ---------------- GEMM1 via f16 MFMA: h1f = f16(x @ W1)  [NN,256]x[256,64] ----------------
#define KP 128
#define XS_LD 136   // 128 + 8 f16 pad

__global__ __launch_bounds__(256) void k_gemm1(const float* __restrict__ x,
                                               const _Float16* __restrict__ wt_g,
                                               _Float16* __restrict__ h1f) {
    __shared__ _Float16 xs[64 * XS_LD];
    __shared__ _Float16 wt[64 * XS_LD];
    int nb = blockIdx.x * 64;
    int tid = threadIdx.x;
    int w = tid >> 6, l = tid & 63;
    int r16 = l & 15, g = l >> 4;

    f32x4 acc[4] = {{0.f,0.f,0.f,0.f},{0.f,0.f,0.f,0.f},{0.f,0.f,0.f,0.f},{0.f,0.f,0.f,0.f}};

    #pragma unroll
    for (int p = 0; p < 2; ++p) {
        int k0 = p * KP;
        __syncthreads();
        for (int i = tid; i < 64 * 32; i += 256) {
            int r = i >> 5, c = (i & 31) * 4;
            float4 v = make_float4(0.f, 0.f, 0.f, 0.f);
            if (nb + r < NN) v = *(const float4*)&x[(size_t)(nb + r) * FIN + k0 + c];
            half4 h; h[0] = (_Float16)v.x; h[1] = (_Float16)v.y;
                     h[2] = (_Float16)v.z; h[3] = (_Float16)v.w;
            *(half4*)&xs[r * XS_LD + c] = h;
        }
        for (int i = tid; i < 64 * 16; i += 256) {
            int r = i >> 4, c = (i & 15) * 8;
            *(half8*)&wt[r * XS_LD + c] = *(const half8*)&wt_g[r * FIN + k0 + c];
        }
        __syncthreads();
        #pragma unroll
        for (int ks = 0; ks < 4; ++ks) {
            int kk = ks * 32 + g * 8;
            half8 a = *(const half8*)&xs[(w * 16 + r16) * XS_LD + kk];
            #pragma unroll
            for (int fb = 0; fb < 4; ++fb) {
                half8 b = *(const half8*)&wt[(fb * 16 + r16) * XS_LD + kk];
                acc[fb] = __builtin_amdgcn_mfma_f32_16x16x32_f16(a, b, acc[fb], 0, 0, 0);
            }
        }
    }
    int nodeb = nb + w * 16 + g * 4;
    #pragma unroll
    for (int fb = 0; fb < 4; ++fb) {
        #pragma unroll
        for (int r = 0; r < 4; ++r) {
            int node = nodeb + r;
            if (node < NN) h1f[(size_t)node * FH + fb * 16 + r16] = (_Float16)acc[fb][r];
        }
    }
}

// ---------------- gather1: h2 = relu(dd*(Σ dinv[s] h1[s] + dd h1[d]) + b1) ----------------
// One dst per wave. lane = es*16+fg (es: edge slot 0..3, fg: half4 feature group
// 0..15). 4 edges in flight per load instr; butterfly-reduce over es.
__global__ __launch_bounds__(256) void k_gather1(const _Float16* __restrict__ h1f,
                                                 const float* __restrict__ dinv,
                                                 const int* __restrict__ row_start,
                                                 const int* __restrict__ ideg,
                                                 const int* __restrict__ csr_src,
                                                 const float* __restrict__ b1,
                                                 float* __restrict__ h2) {
    int d = blockIdx.x * 4 + (threadIdx.x >> 6);   // 12500 blocks * 4 waves, exact
    int lane = threadIdx.x & 63;
    int es = lane >> 4, fg = lane & 15;
    int row = row_start[d];
    int cnt = ideg[d];
    float dd = dinv[d];
    float4 acc = make_float4(0.f, 0.f, 0.f, 0.f);
    if (es == 0) {   // self-loop term
        half4 hv = *(const half4*)&h1f[(size_t)d * FH + fg * 4];
        acc.x = dd * (float)hv[0]; acc.y = dd * (float)hv[1];
        acc.z = dd * (float)hv[2]; acc.w = dd * (float)hv[3];
    }
    for (int j = es; j < cnt; j += 4) {
        int s = csr_src[row + j];
        float w = dinv[s];
        half4 hv = *(const half4*)&h1f[(size_t)s * FH + fg * 4];
        acc.x += w * (float)hv[0]; acc.y += w * (float)hv[1];
        acc.z += w * (float)hv[2]; acc.w += w * (float)hv[3];
    }
    #pragma unroll
    for (int m = 16; m <= 32; m <<= 1) {
        acc.x += __shfl_xor(acc.x, m, 64);
        acc.y += __shfl_xor(acc.y, m, 64);
        acc.z += __shfl_xor(acc.z, m, 64);
        acc.w += __shfl_xor(acc.w, m, 64);
    }
    if (lane < 16) {
        float4 bv = *(const float4*)&b1[fg * 4];
        float4 r;
        r.x = fmaxf(acc.x * dd + bv.x, 0.f);
        r.y = fmaxf(acc.y * dd + bv.y, 0.f);
        r.z = fmaxf(acc.z * dd + bv.z, 0.f);
        r.w = fmaxf(acc.w * dd + bv.w, 0.f);
        *(float4*)&h2[(size_t)d * FH + fg * 4] = r;
    }
}

// ---------------- GEMM2: h3f = f16(h2 @ W2)  [NN,64]x[64,32] ----------------
__global__ __launch_bounds__(256) void k_gemm2(const float* __restrict__ h2,
                                               const float* __restrict__ W2,
                                               _Float16* __restrict__ h3f) {
    __shared__ float xs[64 * FH];  // 16 KB
    int nb = blockIdx.x * 64;
    for (int idx = threadIdx.x; idx < 64 * (FH / 4); idx += 256) {
        int r = idx >> 4;
        int c = (idx & 15) * 4;
        float4 v = make_float4(0.f, 0.f, 0.f, 0.f);
        if (nb + r < NN) v = *(const float4*)&h2[(size_t)(nb + r) * FH + c];
        *(float4*)&xs[r * FH + ((c + 4 * r) & (FH - 1))] = v;
    }
    __syncthreads();

    int f0 = (threadIdx.x & 7) * 4;
    int n0 = (threadIdx.x >> 3) * 2;
    const float* wp = W2 + f0;
    float4 a0 = make_float4(0.f, 0.f, 0.f, 0.f);
    float4 a1 = a0;
    #pragma unroll 4
    for (int k = 0; k < FH; k += 4) {
        float4 w0 = *(const float4*)&wp[(k + 0) * FL];
        float4 w1 = *(const float4*)&wp[(k + 1) * FL];
        float4 w2 = *(const float4*)&wp[(k + 2) * FL];
        float4 w3 = *(const float4*)&wp[(k + 3) * FL];
        float4 x0 = *(const float4*)&xs[(n0 + 0) * FH + ((k + 4 * (n0 + 0)) & (FH - 1))];
        float4 x1 = *(const float4*)&xs[(n0 + 1) * FH + ((k + 4 * (n0 + 1)) & (FH - 1))];
        a0.x += x0.x*w0.x + x0.y*w1.x + x0.z*w2.x + x0.w*w3.x;
        a0.y += x0.x*w0.y + x0.y*w1.y + x0.z*w2.y + x0.w*w3.y;
        a0.z += x0.x*w0.z + x0.y*w1.z + x0.z*w2.z + x0.w*w3.z;
        a0.w += x0.x*w0.w + x0.y*w1.w + x0.z*w2.w + x0.w*w3.w;
        a1.x += x1.x*w0.x + x1.y*w1.x + x1.z*w2.x + x1.w*w3.x;
        a1.y += x1.x*w0.y + x1.y*w1.y + x1.z*w2.y + x1.w*w3.y;
        a1.z += x1.x*w0.z + x1.y*w1.z + x1.z*w2.z + x1.w*w3.z;
        a1.w += x1.x*w0.w + x1.y*w1.w + x1.z*w2.w + x1.w*w3.w;
    }
    int g0 = nb + n0;
    if (g0 + 0 < NN) {
        half4 h; h[0]=(_Float16)a0.x; h[1]=(_Float16)a0.y; h[2]=(_Float16)a0.z; h[3]=(_Float16)a0.w;
        *(half4*)&h3f[(size_t)(g0 + 0) * FL + f0] = h;
    }
    if (g0 + 1 < NN) {
        half4 h; h[0]=(_Float16)a1.x; h[1]=(_Float16)a1.y; h[2]=(_Float16)a1.z; h[3]=(_Float16)a1.w;
        *(half4*)&h3f[(size_t)(g0 + 1) * FL + f0] = h;
    }
}

// ---------------- gather2: out = dd*(Σ dinv[s] h3[s] + dd h3[d]) + b2 ----------------
// One dst per wave. lane = es*8+fg (es: edge slot 0..7, fg: half4 group 0..7).
__global__ __launch_bounds__(256) void k_gather2(const _Float16* __restrict__ h3f,
                                                 const float* __restrict__ dinv,
                                                 const int* __restrict__ row_start,
                                                 const int* __restrict__ ideg,
                                                 const int* __restrict__ csr_src,
                                                 const float* __restrict__ b2,
                                                 float* __restrict__ out) {
    int d = blockIdx.x * 4 + (threadIdx.x >> 6);
    int lane = threadIdx.x & 63;
    int es = lane >> 3, fg = lane & 7;
    int row = row_start[d];
    int cnt = ideg[d];
    float dd = dinv[d];
    float4 acc = make_float4(0.f, 0.f, 0.f, 0.f);
    if (es == 0) {
        half4 hv = *(const half4*)&h3f[(size_t)d * FL + fg * 4];
        acc.x = dd * (float)hv[0]; acc.y = dd * (float)hv[1];
        acc.z = dd * (float)hv[2]; acc.w = dd * (float)hv[3];
    }
    for (int j = es; j < cnt; j += 8) {
        int s = csr_src[row + j];
        float w = dinv[s];
        half4 hv = *(const half4*)&h3f[(size_t)s * FL + fg * 4];
        acc.x += w * (float)hv[0]; acc.y += w * (float)hv[1];
        acc.z += w * (float)hv[2]; acc.w += w * (float)hv[3];
    }
    #pragma unroll
    for (int m = 8; m <= 32; m <<= 1) {
        acc.x += __shfl_xor(acc.x, m, 64);
        acc.y += __shfl_xor(acc.y, m, 64);
        acc.z += __shfl_xor(acc.z, m, 64);
        acc.w += __shfl_xor(acc.w, m, 64);
    }
    if (lane < 8) {
        float4 bv = *(const float4*)&b2[fg * 4];
        float4 r;
        r.x = acc.x * dd + bv.x;
        r.y = acc.y * dd + bv.y;
        r.z = acc.z * dd + bv.z;
        r.w = acc.w * dd + bv.w;
        *(float4*)&out[(size_t)d * FL + fg * 4] = r;
    }
}

extern "C" void kernel_launch(void* const* d_in, const int* in_sizes, int n_in,
                              void* d_out, int out_size, void* d_ws, size_t ws_size,
                              hipStream_t stream) {
    const float* x  = (const float*)d_in[0];
    const int*   ei = (const int*)d_in[1];   // [2, NE] int32
    const float* W1 = (const float*)d_in[2];
    const float* b1 = (const float*)d_in[3];
    const float* W2 = (const float*)d_in[4];
    const float* b2 = (const float*)d_in[5];
    float* out = (float*)d_out;

    const int* src = ei;
    const int* dst = ei + NE;

    // ws layout (<= 30.3 MB, same envelope as R4):
    //  0.00M dinv(200K) | 0.25M ideg(200K) | 0.50M partials(1K) | 0.55M wt_g(32K)
    //  0.75M row_start(200K) | 1.00M head(200K) | 1.25M csr_src(3.2M)
    //  4.50M h1f(6.4M f16, reused as h3f) | 11.0M nxt2(6.4M) | 17.5M h2(12.8M)
    char* ws = (char*)d_ws;
    float*     dinv     = (float*)(ws);
    int*       ideg     = (int*)(ws + (size_t)(1u << 18));
    int*       partials = (int*)(ws + (size_t)(1u << 19));
    _Float16*  wt_g     = (_Float16*)(ws + (size_t)(1u << 19) + (1u << 16));
    int*       row_start= (int*)(ws + (size_t)3 * (1u << 18));
    int*       head     = (int*)(ws + (size_t)(1u << 20));
    int*       csr_src  = (int*)(ws + (size_t)(1u << 20) + (1u << 18));
    _Float16*  h1f      = (_Float16*)(ws + (size_t)45 * (1u << 20) / 10);
    int2*      nxt2     = (int2*)(ws + (size_t)11 * (1u << 20));
    float*     h2       = (float*)(ws + (size_t)175 * (1u << 20) / 10);
    _Float16*  h3f      = h1f;   // alias: h1f dead after gather1

    // --- CSR build + dinv ---
    hipMemsetAsync(ideg, 0, NN * sizeof(int), stream);
    hipMemsetAsync(head, 0xFF, NN * sizeof(int), stream);   // head = -1
    hipLaunchKernelGGL(k_hist, dim3((NE + 255) / 256), dim3(256), 0, stream, dst, ideg);
    hipLaunchKernelGGL(k_scan1, dim3(NBLK), dim3(SCAN_B), 0, stream, ideg, row_start, partials);
    hipLaunchKernelGGL(k_scan2, dim3(1), dim3(SCAN_B), 0, stream, partials);
    hipLaunchKernelGGL(k_scan3, dim3(NBLK), dim3(SCAN_B), 0, stream, row_start, partials, ideg, dinv);
    hipLaunchKernelGGL(k_ll_build, dim3((NE + 255) / 256), dim3(256), 0, stream, src, dst, head, nxt2);
    hipLaunchKernelGGL(k_walk, dim3((NN + 255) / 256), dim3(256), 0, stream, head, nxt2, row_start, csr_src);

    // --- layer 1 ---
    hipLaunchKernelGGL(k_prepW, dim3((FIN * FH + 255) / 256), dim3(256), 0, stream, W1, wt_g);
    hipLaunchKernelGGL(k_gemm1, dim3((NN + 63) / 64), dim3(256), 0, stream, x, wt_g, h1f);
    hipLaunchKernelGGL(k_gather1, dim3(NN / 4), dim3(256), 0, stream,
                       h1f, dinv, row_start, ideg, csr_src, b1, h2);

    // --- layer 2 ---
    hipLaunchKernelGGL(k_gemm2, dim3((NN + 63) / 64), dim3(256), 0, stream, h2, W2, h3f);
    hipLaunchKernelGGL(k_gather2, dim3(NN / 4), dim3(256), 0, stream,
                       h3f, dinv, row_start, ideg, csr_src, b2, out);
}